// Round 3
// baseline (491.387 us; speedup 1.0000x reference)
//
#include <hip/hip_runtime.h>
#include <math.h>

// Problem constants: x = (16, 32, 65536) fp32. One block per row.
// NT=512 (8 waves) -> only 2 waves/SIMD required -> VGPR cap 256, so the
// 128-float/thread register-resident row does NOT spill (round-2 lesson:
// NT=1024 caps VGPRs at 128 and the compiler demoted data[] to scratch,
// VGPR_Count=52, +800MB scratch traffic).
#define LROW   65536
#define NROWS  512              // 16*32
#define NT     512              // threads per block (8 waves)
#define NW     (NT / 64)        // 8 waves
#define EPT    (LROW / NT)      // 128 elements per thread, register-resident
#define HALO   5

#define TREND_SCALING       0.6f
#define DETAIL_PRESERVATION 0.85f
#define SPIKE_THRESHOLD     3.5f
#define SPIKE_DAMPING       0.35f
#define EPSV                1e-6f

// Element accessor over [ -5, EPT+4 ]: halo regs outside, data inside.
// Only used with compile-time-constant indices inside fully-unrolled loops,
// so the select folds away and everything stays in registers.
#define X(i) ((i) < 0 ? hl[(i) + 5] : ((i) >= EPT ? hr[(i) - EPT] : data[(i)]))

// ---------------------------------------------------------------------------
// k_fused: entire 2-iteration denoise for one row per block.
//   - row data register-resident (128 floats/thread, cap 256 VGPR)
//   - per-iteration: LDS halo exchange -> residual stats (f64, deterministic
//     order: 64-lane butterfly + 8 wave partials summed in fixed order by
//     every thread) -> threshold -> in-place apply (shift-by-5 scheme)
//   - row 'reflect' padding handled at tid 0 / NT-1 (block == full row)
// No cross-block dependencies, no workspace, single launch.
// Minimum possible traffic: read x once (134 MB), write out once (134 MB).
// ---------------------------------------------------------------------------
__global__ __launch_bounds__(NT, 2) void k_fused(const float* __restrict__ x,
                                                 float* __restrict__ out,
                                                 const float* __restrict__ k5,
                                                 const float* __restrict__ k11) {
    __shared__ float eL[NT * 5];    // each thread's first 5 elements
    __shared__ float eR[NT * 5];    // each thread's last 5 elements
    __shared__ double wred[2 * NW]; // per-wave (s, q) partials

    const int row = blockIdx.x;
    const int tid = threadIdx.x;
    const size_t base = (size_t)row * LROW + (size_t)tid * EPT;
    const float w5 = k5[0];
    const float w11 = k11[0];

    float data[EPT];
    {
        const float4* g4 = (const float4*)(x + base);
#pragma unroll
        for (int j = 0; j < EPT / 4; j++) {
            float4 t = g4[j];
            data[4 * j] = t.x;
            data[4 * j + 1] = t.y;
            data[4 * j + 2] = t.z;
            data[4 * j + 3] = t.w;
        }
    }

    float hl[5], hr[5], t5[5];

#pragma unroll 1   // keep the iteration loop runtime: one body copy in I-cache
    for (int it = 0; it < 2; ++it) {
        // ---- halo exchange (edges of each thread's 128-element span) ----
#pragma unroll
        for (int j = 0; j < 5; j++) {
            eL[tid * 5 + j] = data[j];
            eR[tid * 5 + j] = data[EPT - 5 + j];
        }
        __syncthreads();   // also protects WAR on wred from previous iteration
        if (tid == 0) {
            // positions -1-j reflect to x[1+j]  ->  hl[j] = x[5-j]
#pragma unroll
            for (int j = 0; j < 5; j++) hl[j] = data[5 - j];
        } else {
#pragma unroll
            for (int j = 0; j < 5; j++) hl[j] = eR[(tid - 1) * 5 + j];
        }
        if (tid == NT - 1) {
            // positions LROW+j reflect to x[LROW-2-j] -> local data[EPT-2-j]
#pragma unroll
            for (int j = 0; j < 5; j++) hr[j] = data[EPT - 2 - j];
        } else {
#pragma unroll
            for (int j = 0; j < 5; j++) hr[j] = eL[(tid + 1) * 5 + j];
        }

        // ---- residual stats: r = cur - box5(cur), f64 accumulation ----
        double s = 0.0, q = 0.0;
#pragma unroll
        for (int k = 0; k < EPT; k++) {
            float lac = 0.f;
#pragma unroll
            for (int d = 0; d < 5; d++) lac = fmaf(X(k - 2 + d), w5, lac);
            float r = data[k] - lac;
            s += (double)r;
            q += (double)r * (double)r;
        }
#pragma unroll
        for (int off = 32; off > 0; off >>= 1) {
            s += __shfl_xor(s, off);
            q += __shfl_xor(q, off);
        }
        {
            const int lane = tid & 63, wid = tid >> 6;
            if (lane == 0) { wred[wid] = s; wred[wid + NW] = q; }
        }
        __syncthreads();   // also protects WAR on eL/eR (all reads done above)

        // every thread redundantly finalizes threshold (fixed order, f64)
        double S = 0.0, Q = 0.0;
#pragma unroll
        for (int w = 0; w < NW; w++) { S += wred[w]; Q += wred[w + NW]; }
        const double N = (double)LROW;
        double var = (Q - S * S / N) / (N - 1.0);
        if (var < 0.0) var = 0.0;
        const float th = fmaxf((float)sqrt(var), EPSV) * SPIKE_THRESHOLD;

        // ---- apply: o[k] from x[k-5..k+5]; write o[k] into data[k-5]
        // (x[k-5] is dead once element k is computed), first 5 into t5.
#pragma unroll
        for (int k = 0; k < EPT; k++) {
            float lac = 0.f, tac = 0.f;
#pragma unroll
            for (int d = 0; d < 5; d++) lac = fmaf(X(k - 2 + d), w5, lac);
#pragma unroll
            for (int d = 0; d < 11; d++) tac = fmaf(X(k - 5 + d), w11, tac);
            float cur = data[k];
            float r = cur - lac;
            r = (fabsf(r) > th) ? r * SPIKE_DAMPING : r;
            float comb = (1.0f - TREND_SCALING) * lac + TREND_SCALING * tac;
            float o = comb + DETAIL_PRESERVATION * r;
            if (k < 5) t5[k] = o; else data[k - 5] = o;
        }
        // shift back so data[k] == o[k]
#pragma unroll
        for (int j = EPT - 1; j >= 5; j--) data[j] = data[j - 5];
#pragma unroll
        for (int j = 0; j < 5; j++) data[j] = t5[j];
    }

    // ---- store final result ----
    {
        float4* o4 = (float4*)(out + base);
#pragma unroll
        for (int j = 0; j < EPT / 4; j++) {
            o4[j] = make_float4(data[4 * j], data[4 * j + 1],
                                data[4 * j + 2], data[4 * j + 3]);
        }
    }
}

extern "C" void kernel_launch(void* const* d_in, const int* in_sizes, int n_in,
                              void* d_out, int out_size, void* d_ws, size_t ws_size,
                              hipStream_t stream) {
    (void)in_sizes; (void)n_in; (void)out_size; (void)d_ws; (void)ws_size;
    const float* x = (const float*)d_in[0];
    const float* k5 = (const float*)d_in[1];
    const float* k11 = (const float*)d_in[2];
    float* out = (float*)d_out;

    hipLaunchKernelGGL(k_fused, dim3(NROWS), dim3(NT), 0, stream, x, out, k5, k11);
}

// Round 4
// 330.005 us; speedup vs baseline: 1.4890x; 1.4890x over previous
//
#include <hip/hip_runtime.h>
#include <math.h>

// Problem constants: x = (16, 32, 65536) fp32. One block per row.
// NT=512 (8 waves) -> 2 waves/SIMD minimum -> VGPR cap 256.
// Round-2/3 lesson: a runtime iteration loop carrying data[128] across a
// back-edge (plus a 123-step shift loop) makes the allocator demote the
// whole array to scratch (VGPR=68, +900MB scratch traffic). This version is
// straight-line (2 inlined iteration bodies), overwrites data[] in place via
// a 5-deep rolling window of originals, and does a divergence-free halo
// exchange through padded LDS edge arrays.
#define LROW   65536
#define NROWS  512              // 16*32
#define NT     512              // threads per block (8 waves)
#define NW     (NT / 64)        // 8 waves
#define EPT    (LROW / NT)      // 128 elements per thread, register-resident

#define TREND_SCALING       0.6f
#define DETAIL_PRESERVATION 0.85f
#define SPIKE_THRESHOLD     3.5f
#define SPIKE_DAMPING       0.35f
#define EPSV                1e-6f

// Stats-phase accessor over [-5, EPT+4]; all uses have compile-time indices.
#define X(i) ((i) < 0 ? hl[(i) + 5] : ((i) >= EPT ? hr[(i) - EPT] : data[(i)]))

// ---------------------------------------------------------------------------
// One full denoise iteration on register-resident data. Straight-line when
// inlined; all data[] indices are compile-time constants.
//   eRpad[t*5+j] : x-positions (t*EPT -5+j)   (left halo of thread t)
//   eLpad[t*5+j] : first-5 of thread t; slot NT = right reflect
// ---------------------------------------------------------------------------
__device__ __forceinline__ void iter_once(float (&data)[EPT], const int tid,
                                          const float w5, const float w11,
                                          float* __restrict__ eLpad,
                                          float* __restrict__ eRpad,
                                          double* __restrict__ wred) {
    // ---- publish edges (uniform), boundary threads add reflect values ----
#pragma unroll
    for (int j = 0; j < 5; j++) {
        eLpad[tid * 5 + j] = data[j];
        eRpad[(tid + 1) * 5 + j] = data[EPT - 5 + j];
    }
    if (tid == 0) {
        // hl[j] = x[-5+j] = x[5-j]  (reflect)
#pragma unroll
        for (int j = 0; j < 5; j++) eRpad[j] = data[5 - j];
    }
    if (tid == NT - 1) {
        // hr[j] = x[L+j] = x[L-2-j] (reflect) -> local data[EPT-2-j]
#pragma unroll
        for (int j = 0; j < 5; j++) eLpad[NT * 5 + j] = data[EPT - 2 - j];
    }
    __syncthreads();

    float hl[5], hr[5];
#pragma unroll
    for (int j = 0; j < 5; j++) {
        hl[j] = eRpad[tid * 5 + j];          // x[base-5+j]
        hr[j] = eLpad[(tid + 1) * 5 + j];    // x[base+EPT+j]
    }

    // ---- residual stats: r = cur - box5(cur), f64, deterministic order ----
    double s = 0.0, q = 0.0;
#pragma unroll
    for (int k = 0; k < EPT; k++) {
        float lac = 0.f;
#pragma unroll
        for (int d = 0; d < 5; d++) lac = fmaf(X(k - 2 + d), w5, lac);
        float r = data[k] - lac;
        s += (double)r;
        q += (double)r * (double)r;
    }
#pragma unroll
    for (int off = 32; off > 0; off >>= 1) {
        s += __shfl_xor(s, off);
        q += __shfl_xor(q, off);
    }
    if ((tid & 63) == 0) {
        wred[tid >> 6] = s;
        wred[(tid >> 6) + NW] = q;
    }
    __syncthreads();

    // every thread redundantly finalizes threshold (fixed order, f64)
    double S = 0.0, Q = 0.0;
#pragma unroll
    for (int w = 0; w < NW; w++) { S += wred[w]; Q += wred[w + NW]; }
    const double N = (double)LROW;
    double var = (Q - S * S / N) / (N - 1.0);
    if (var < 0.0) var = 0.0;
    const float th = fmaxf((float)sqrt(var), EPSV) * SPIKE_THRESHOLD;

    // ---- apply in place: rolling window p0..p4 = originals x[k-5..k-1] ----
    float p0 = hl[0], p1 = hl[1], p2 = hl[2], p3 = hl[3], p4 = hl[4];
#pragma unroll
    for (int k = 0; k < EPT; k++) {
        const float cur = data[k];
        const float xp1 = (k + 1 < EPT) ? data[k + 1] : hr[k + 1 - EPT];
        const float xp2 = (k + 2 < EPT) ? data[k + 2] : hr[k + 2 - EPT];
        const float xp3 = (k + 3 < EPT) ? data[k + 3] : hr[k + 3 - EPT];
        const float xp4 = (k + 4 < EPT) ? data[k + 4] : hr[k + 4 - EPT];
        const float xp5 = (k + 5 < EPT) ? data[k + 5] : hr[k + 5 - EPT];
        // lac: d=0..4 over x[k-2+d]  (same fmaf order as passing versions)
        float lac = 0.f;
        lac = fmaf(p3, w5, lac);
        lac = fmaf(p4, w5, lac);
        lac = fmaf(cur, w5, lac);
        lac = fmaf(xp1, w5, lac);
        lac = fmaf(xp2, w5, lac);
        // tac: d=0..10 over x[k-5+d]
        float tac = 0.f;
        tac = fmaf(p0, w11, tac);
        tac = fmaf(p1, w11, tac);
        tac = fmaf(p2, w11, tac);
        tac = fmaf(p3, w11, tac);
        tac = fmaf(p4, w11, tac);
        tac = fmaf(cur, w11, tac);
        tac = fmaf(xp1, w11, tac);
        tac = fmaf(xp2, w11, tac);
        tac = fmaf(xp3, w11, tac);
        tac = fmaf(xp4, w11, tac);
        tac = fmaf(xp5, w11, tac);
        float r = cur - lac;
        r = (fabsf(r) > th) ? r * SPIKE_DAMPING : r;
        const float comb = (1.0f - TREND_SCALING) * lac + TREND_SCALING * tac;
        data[k] = comb + DETAIL_PRESERVATION * r;
        p0 = p1; p1 = p2; p2 = p3; p3 = p4; p4 = cur;
    }
}

// ---------------------------------------------------------------------------
// k_fused: entire 2-iteration denoise, one row per block, data in registers.
// Minimum traffic: read x once (134 MB), write out once (134 MB).
// ---------------------------------------------------------------------------
__global__ __launch_bounds__(NT, 2) void k_fused(const float* __restrict__ x,
                                                 float* __restrict__ out,
                                                 const float* __restrict__ k5,
                                                 const float* __restrict__ k11) {
    __shared__ float eLpad[(NT + 1) * 5];
    __shared__ float eRpad[(NT + 1) * 5];
    __shared__ double wred[2 * NW];

    const int row = blockIdx.x;
    const int tid = threadIdx.x;
    const size_t base = (size_t)row * LROW + (size_t)tid * EPT;
    const float w5 = k5[0];
    const float w11 = k11[0];

    float data[EPT];
    {
        const float4* g4 = (const float4*)(x + base);
#pragma unroll
        for (int j = 0; j < EPT / 4; j++) {
            float4 t = g4[j];
            data[4 * j] = t.x;
            data[4 * j + 1] = t.y;
            data[4 * j + 2] = t.z;
            data[4 * j + 3] = t.w;
        }
    }

    iter_once(data, tid, w5, w11, eLpad, eRpad, wred);
    iter_once(data, tid, w5, w11, eLpad, eRpad, wred);

    {
        float4* o4 = (float4*)(out + base);
#pragma unroll
        for (int j = 0; j < EPT / 4; j++) {
            o4[j] = make_float4(data[4 * j], data[4 * j + 1],
                                data[4 * j + 2], data[4 * j + 3]);
        }
    }
}

extern "C" void kernel_launch(void* const* d_in, const int* in_sizes, int n_in,
                              void* d_out, int out_size, void* d_ws, size_t ws_size,
                              hipStream_t stream) {
    (void)in_sizes; (void)n_in; (void)out_size; (void)d_ws; (void)ws_size;
    const float* x = (const float*)d_in[0];
    const float* k5 = (const float*)d_in[1];
    const float* k11 = (const float*)d_in[2];
    float* out = (float*)d_out;

    hipLaunchKernelGGL(k_fused, dim3(NROWS), dim3(NT), 0, stream, x, out, k5, k11);
}

// Round 5
// 316.864 us; speedup vs baseline: 1.5508x; 1.0415x over previous
//
#include <hip/hip_runtime.h>
#include <math.h>

// Problem constants: x = (16, 32, 65536) fp32. One block per row.
//
// Register-budget design (round-4 lesson): the backend allocates to a
// 128-VGPR / 4-waves-per-SIMD target. EPT=128 (NT=512) needs >128 regs ->
// partial spill (165 MB scratch writes). So: NT=1024, EPT=64. Live set
// ~= 64 data + 10 halo + 5 rolling + f64 accs + temps ~= 100 regs < 128.
// A 16-wave workgroup requires 4 waves/SIMD anyway, so 128 is also the hard
// cap -- the design and the allocator target coincide. Structure stays the
// round-4 straight-line / rolling-window form that allocates cleanly
// (round-2's runtime loop + shift loop caused wholesale demotion).
#define LROW   65536
#define NROWS  512              // 16*32
#define NT     1024             // threads per block (16 waves)
#define NW     (NT / 64)        // 16 waves
#define EPT    (LROW / NT)      // 64 elements per thread, register-resident

#define TREND_SCALING       0.6f
#define DETAIL_PRESERVATION 0.85f
#define SPIKE_THRESHOLD     3.5f
#define SPIKE_DAMPING       0.35f
#define EPSV                1e-6f

// Stats-phase accessor over [-5, EPT+4]; all uses have compile-time indices.
#define X(i) ((i) < 0 ? hl[(i) + 5] : ((i) >= EPT ? hr[(i) - EPT] : data[(i)]))

// ---------------------------------------------------------------------------
// One full denoise iteration on register-resident data. Straight-line when
// inlined; all data[] indices are compile-time constants.
//   eRpad[t*5+j]      : x-positions (t*EPT - 5 + j)  (left halo of thread t)
//   eLpad[t*5+j]      : first-5 of thread t; slot NT = right reflect
// ---------------------------------------------------------------------------
__device__ __forceinline__ void iter_once(float (&data)[EPT], const int tid,
                                          const float w5, const float w11,
                                          float* __restrict__ eLpad,
                                          float* __restrict__ eRpad,
                                          double* __restrict__ wred) {
    // ---- publish edges (uniform), boundary threads add reflect values ----
#pragma unroll
    for (int j = 0; j < 5; j++) {
        eLpad[tid * 5 + j] = data[j];
        eRpad[(tid + 1) * 5 + j] = data[EPT - 5 + j];
    }
    if (tid == 0) {
        // hl[j] = x[-5+j] = x[5-j]  (reflect)
#pragma unroll
        for (int j = 0; j < 5; j++) eRpad[j] = data[5 - j];
    }
    if (tid == NT - 1) {
        // hr[j] = x[L+j] = x[L-2-j] (reflect) -> local data[EPT-2-j]
#pragma unroll
        for (int j = 0; j < 5; j++) eLpad[NT * 5 + j] = data[EPT - 2 - j];
    }
    __syncthreads();

    float hl[5], hr[5];
#pragma unroll
    for (int j = 0; j < 5; j++) {
        hl[j] = eRpad[tid * 5 + j];          // x[base-5+j]
        hr[j] = eLpad[(tid + 1) * 5 + j];    // x[base+EPT+j]
    }

    // ---- residual stats: r = cur - box5(cur), f64, deterministic order ----
    double s = 0.0, q = 0.0;
#pragma unroll
    for (int k = 0; k < EPT; k++) {
        float lac = 0.f;
#pragma unroll
        for (int d = 0; d < 5; d++) lac = fmaf(X(k - 2 + d), w5, lac);
        float r = data[k] - lac;
        s += (double)r;
        q += (double)r * (double)r;
    }
#pragma unroll
    for (int off = 32; off > 0; off >>= 1) {
        s += __shfl_xor(s, off);
        q += __shfl_xor(q, off);
    }
    if ((tid & 63) == 0) {
        wred[tid >> 6] = s;
        wred[(tid >> 6) + NW] = q;
    }
    __syncthreads();

    // every thread redundantly finalizes threshold (fixed order, f64)
    double S = 0.0, Q = 0.0;
#pragma unroll
    for (int w = 0; w < NW; w++) { S += wred[w]; Q += wred[w + NW]; }
    const double N = (double)LROW;
    double var = (Q - S * S / N) / (N - 1.0);
    if (var < 0.0) var = 0.0;
    const float th = fmaxf((float)sqrt(var), EPSV) * SPIKE_THRESHOLD;

    // ---- apply in place: rolling window p0..p4 = originals x[k-5..k-1] ----
    float p0 = hl[0], p1 = hl[1], p2 = hl[2], p3 = hl[3], p4 = hl[4];
#pragma unroll
    for (int k = 0; k < EPT; k++) {
        const float cur = data[k];
        const float xp1 = (k + 1 < EPT) ? data[k + 1] : hr[k + 1 - EPT];
        const float xp2 = (k + 2 < EPT) ? data[k + 2] : hr[k + 2 - EPT];
        const float xp3 = (k + 3 < EPT) ? data[k + 3] : hr[k + 3 - EPT];
        const float xp4 = (k + 4 < EPT) ? data[k + 4] : hr[k + 4 - EPT];
        const float xp5 = (k + 5 < EPT) ? data[k + 5] : hr[k + 5 - EPT];
        // lac: d=0..4 over x[k-2+d]  (same fmaf order as passing versions)
        float lac = 0.f;
        lac = fmaf(p3, w5, lac);
        lac = fmaf(p4, w5, lac);
        lac = fmaf(cur, w5, lac);
        lac = fmaf(xp1, w5, lac);
        lac = fmaf(xp2, w5, lac);
        // tac: d=0..10 over x[k-5+d]
        float tac = 0.f;
        tac = fmaf(p0, w11, tac);
        tac = fmaf(p1, w11, tac);
        tac = fmaf(p2, w11, tac);
        tac = fmaf(p3, w11, tac);
        tac = fmaf(p4, w11, tac);
        tac = fmaf(cur, w11, tac);
        tac = fmaf(xp1, w11, tac);
        tac = fmaf(xp2, w11, tac);
        tac = fmaf(xp3, w11, tac);
        tac = fmaf(xp4, w11, tac);
        tac = fmaf(xp5, w11, tac);
        float r = cur - lac;
        r = (fabsf(r) > th) ? r * SPIKE_DAMPING : r;
        const float comb = (1.0f - TREND_SCALING) * lac + TREND_SCALING * tac;
        data[k] = comb + DETAIL_PRESERVATION * r;
        p0 = p1; p1 = p2; p2 = p3; p3 = p4; p4 = cur;
    }
}

// ---------------------------------------------------------------------------
// k_fused: entire 2-iteration denoise, one row per block, data in registers.
// Minimum traffic: read x once (134 MB), write out once (134 MB).
// ---------------------------------------------------------------------------
__global__ void __attribute__((amdgpu_flat_work_group_size(NT, NT),
                               amdgpu_waves_per_eu(4, 4)))
k_fused(const float* __restrict__ x, float* __restrict__ out,
        const float* __restrict__ k5, const float* __restrict__ k11) {
    __shared__ float eLpad[(NT + 1) * 5];
    __shared__ float eRpad[(NT + 1) * 5];
    __shared__ double wred[2 * NW];

    const int row = blockIdx.x;
    const int tid = threadIdx.x;
    const size_t base = (size_t)row * LROW + (size_t)tid * EPT;
    const float w5 = k5[0];
    const float w11 = k11[0];

    float data[EPT];
    {
        const float4* g4 = (const float4*)(x + base);
#pragma unroll
        for (int j = 0; j < EPT / 4; j++) {
            float4 t = g4[j];
            data[4 * j] = t.x;
            data[4 * j + 1] = t.y;
            data[4 * j + 2] = t.z;
            data[4 * j + 3] = t.w;
        }
    }

    iter_once(data, tid, w5, w11, eLpad, eRpad, wred);
    iter_once(data, tid, w5, w11, eLpad, eRpad, wred);

    {
        float4* o4 = (float4*)(out + base);
#pragma unroll
        for (int j = 0; j < EPT / 4; j++) {
            o4[j] = make_float4(data[4 * j], data[4 * j + 1],
                                data[4 * j + 2], data[4 * j + 3]);
        }
    }
}

extern "C" void kernel_launch(void* const* d_in, const int* in_sizes, int n_in,
                              void* d_out, int out_size, void* d_ws, size_t ws_size,
                              hipStream_t stream) {
    (void)in_sizes; (void)n_in; (void)out_size; (void)d_ws; (void)ws_size;
    const float* x = (const float*)d_in[0];
    const float* k5 = (const float*)d_in[1];
    const float* k11 = (const float*)d_in[2];
    float* out = (float*)d_out;

    hipLaunchKernelGGL(k_fused, dim3(NROWS), dim3(NT), 0, stream, x, out, k5, k11);
}